// Round 1
// 515.889 us; speedup vs baseline: 1.1704x; 1.1704x over previous
//
#include <hip/hip_runtime.h>

// HGT encoder, MI355X — ROUND 9.
// R8 analysis: attn_kernel latency-bound (MfmaUtil 0, VALU 35%, HBM 36%,
// occ 40% — nothing saturated; serial dependent-load chain per edge).
// Changes:
//  1. attn: process edges in batches of 4 — issue 4 elist loads + 16 uint4
//     kv loads before computing -> ~16 outstanding VMEM/wave (was ~4).
//     Same summation order, identical numerics.
//  2. Fuse per-type/per-relation GEMM dispatches: 10 GEMM launches/layer -> 3
//     (block -> type/relation lookup inside kernel). Kills launch gaps and
//     314-block tail-wave drains.
// GEMM tile layouts unchanged (guide-verified): A[m=lane&15][k=quad*8+j],
// B[k=quad*8+j][n=lane&15], D[row=quad*4+reg][col=lane&15].

#define NTOT  80000
#define ETOT  600000
#define NSRC  120000

typedef unsigned short u16;
typedef unsigned int   u32;
typedef __attribute__((ext_vector_type(8))) short short8;
typedef __attribute__((ext_vector_type(4))) float f32x4;

__device__ __forceinline__ float bf2f(u16 u){
  union { u32 i; float f; } v; v.i = ((u32)u) << 16; return v.f;
}
__device__ __forceinline__ u16 f2bf(float f){
  union { float f; u32 i; } v; v.f = f;
  u32 x = v.i;
  return (u16)((x + 0x7fffu + ((x >> 16) & 1u)) >> 16);   // RNE
}
__device__ __forceinline__ void unpack8(const u16* p, float* o){
  uint4 a = *(const uint4*)p;
  union { u32 i; float f; } t;
  t.i = a.x << 16;        o[0]=t.f;  t.i = a.x & 0xffff0000u; o[1]=t.f;
  t.i = a.y << 16;        o[2]=t.f;  t.i = a.y & 0xffff0000u; o[3]=t.f;
  t.i = a.z << 16;        o[4]=t.f;  t.i = a.z & 0xffff0000u; o[5]=t.f;
  t.i = a.w << 16;        o[6]=t.f;  t.i = a.w & 0xffff0000u; o[7]=t.f;
}
__device__ __forceinline__ void load16bf(const u16* p, float* o){
  unpack8(p, o); unpack8(p + 8, o + 8);
}
__device__ __forceinline__ void unp4(uint4 a, float* o){
  union { u32 i; float f; } t;
  t.i = a.x << 16;        o[0]=t.f;  t.i = a.x & 0xffff0000u; o[1]=t.f;
  t.i = a.y << 16;        o[2]=t.f;  t.i = a.y & 0xffff0000u; o[3]=t.f;
  t.i = a.z << 16;        o[4]=t.f;  t.i = a.z & 0xffff0000u; o[5]=t.f;
  t.i = a.w << 16;        o[6]=t.f;  t.i = a.w & 0xffff0000u; o[7]=t.f;
}

// ---------------- init ----------------

__global__ __launch_bounds__(256) void copy_init(
    const float* __restrict__ xg, const float* __restrict__ xd,
    const float* __restrict__ xr, float* __restrict__ X)
{
  int i = blockIdx.x * 256 + threadIdx.x;        // float4 units; 2,560,000 total
  if (i >= 2560000) return;
  const float* src; int off;
  if (i < 1600000)      { src = xg; off = i; }
  else if (i < 2240000) { src = xd; off = i - 1600000; }
  else                  { src = xr; off = i - 2240000; }
  ((float4*)X)[i] = ((const float4*)src)[off];
}

__global__ __launch_bounds__(256) void zero_cc(int* __restrict__ cnt, int* __restrict__ cur){
  int i = blockIdx.x * 256 + threadIdx.x;
  if (i < NTOT){ cnt[i] = 0; cur[i] = 0; }
}

// ---------------- CSR build ----------------

__global__ __launch_bounds__(256) void count_edges(const int* __restrict__ ei, int E, int offd,
                            int* __restrict__ cnt){
  int e = blockIdx.x * 256 + threadIdx.x;
  if (e < E) atomicAdd(&cnt[offd + ei[E + e]], 1);
}

__global__ __launch_bounds__(256) void scan_partial(const int* __restrict__ cnt,
                             int* __restrict__ rowp, int* __restrict__ bsum){
  __shared__ int s[256];
  int tid = threadIdx.x;
  int i = blockIdx.x * 256 + tid;
  int v = (i < NTOT) ? cnt[i] : 0;
  s[tid] = v; __syncthreads();
  for (int off = 1; off < 256; off <<= 1){
    int t = (tid >= off) ? s[tid - off] : 0;
    __syncthreads();
    s[tid] += t;
    __syncthreads();
  }
  if (i < NTOT) rowp[i] = s[tid] - v;
  if (tid == 255) bsum[blockIdx.x] = s[255];
}

__global__ __launch_bounds__(256) void scan_block(int* __restrict__ bsum, int nb){
  __shared__ int b[512];
  __shared__ int p[256];
  int tid = threadIdx.x;
  b[tid]       = (tid < nb)       ? bsum[tid]       : 0;
  b[tid + 256] = (tid + 256 < nb) ? bsum[tid + 256] : 0;
  __syncthreads();
  int pv = b[2*tid] + b[2*tid + 1];
  p[tid] = pv; __syncthreads();
  for (int off = 1; off < 256; off <<= 1){
    int t = (tid >= off) ? p[tid - off] : 0;
    __syncthreads();
    p[tid] += t;
    __syncthreads();
  }
  int excl = p[tid] - pv;
  int e0 = excl, e1 = excl + b[2*tid];
  __syncthreads();
  if (2*tid < nb)   bsum[2*tid]     = e0;
  if (2*tid+1 < nb) bsum[2*tid + 1] = e1;
}

__global__ __launch_bounds__(256) void scan_add(int* __restrict__ rowp, const int* __restrict__ bsum){
  int i = blockIdx.x * 256 + threadIdx.x;
  if (i < NTOT) rowp[i] += bsum[i >> 8];
}

__global__ __launch_bounds__(256) void scatter_edges(const int* __restrict__ ei, int E, int offd,
                              int rnoff, int rel,
                              const int* __restrict__ rowp, int* __restrict__ cur,
                              int* __restrict__ elist){
  int e = blockIdx.x * 256 + threadIdx.x;
  if (e >= E) return;
  int src = ei[e], dst = ei[E + e];
  int dstg = offd + dst;
  int pos = atomicAdd(&cur[dstg], 1);
  elist[rowp[dstg] + pos] = ((rnoff + src) << 2) | rel;
}

// ---------------- fold Ak/Av into K/V weights (fp32, exact) ----------------

__global__ __launch_bounds__(256) void build_weff(
    const float* __restrict__ Wkqv, const float* __restrict__ Ak,
    const float* __restrict__ Av, float* __restrict__ Weff)
{
  int lr = blockIdx.y;
  int l = lr >> 2, r = lr & 3;
  int st = (r >= 2) ? 2 : 0;
  int elem = blockIdx.x * 256 + threadIdx.x;     // f*256 + j
  int f = elem >> 8, j = elem & 255;
  const float* W = Wkqv + (size_t)(l*3 + st) * 49152;
  float acc = 0.f;
  if (j < 128){
    int h = j >> 4, e = j & 15;
    const float* Am = Ak + (size_t)(l*4 + r) * 2048 + h*256;
#pragma unroll
    for (int d = 0; d < 16; d++) acc += W[f*384 + h*16 + d] * Am[d*16 + e];
  } else {
    int j2 = j - 128, h = j2 >> 4, e = j2 & 15;
    const float* Am = Av + (size_t)(l*4 + r) * 2048 + h*256;
#pragma unroll
    for (int d = 0; d < 16; d++) acc += W[f*384 + 256 + h*16 + d] * Am[d*16 + e];
  }
  Weff[(size_t)lr * 32768 + elem] = acc;
}

__global__ __launch_bounds__(256) void build_beff(
    const float* __restrict__ bkqv, const float* __restrict__ Ak,
    const float* __restrict__ Av, float* __restrict__ beff)
{
  int lr = blockIdx.x;
  int l = lr >> 2, r = lr & 3;
  int st = (r >= 2) ? 2 : 0;
  int j = threadIdx.x;
  const float* b = bkqv + (size_t)(l*3 + st) * 384;
  float acc = 0.f;
  if (j < 128){
    int h = j >> 4, e = j & 15;
    const float* Am = Ak + (size_t)(l*4 + r) * 2048 + h*256;
#pragma unroll
    for (int d = 0; d < 16; d++) acc += b[h*16 + d] * Am[d*16 + e];
  } else {
    int j2 = j - 128, h = j2 >> 4, e = j2 & 15;
    const float* Am = Av + (size_t)(l*4 + r) * 2048 + h*256;
#pragma unroll
    for (int d = 0; d < 16; d++) acc += b[256 + h*16 + d] * Am[d*16 + e];
  }
  beff[lr * 256 + j] = acc;
}

// ---------------- MFMA GEMM tile body: C(bf16) = A(fp32 Mx128) @ B(fp32 128xN) + bias ----------------
// 64x64 tile / block, 4 waves x 16 rows; 4 n-frags x 16 cols = full 64-wide tile.

#define BTSTR 136   // u16 stride of LDS B^T rows (272 B: 16B-aligned)

__device__ __forceinline__ void gemm_tile_f32A(
    const float* __restrict__ A, const float* __restrict__ B, int ldb,
    const float* __restrict__ bias, u16* __restrict__ C, int ldc,
    int M, int bm, int bn, u16* BT)
{
  int tid = threadIdx.x;
  { // stage B^T (bf16): coalesced global reads, transpose into LDS
    int n = tid & 63, k0 = tid >> 6;
#pragma unroll
    for (int i = 0; i < 32; i++){
      int k = k0 + i*4;
      BT[n*BTSTR + k] = f2bf(B[(size_t)k*ldb + bn + n]);
    }
  }
  __syncthreads();
  int lane = tid & 63, wave = tid >> 6;
  int quad = lane >> 4, lm = lane & 15;
  int row = bm + wave*16 + lm;
  short8 af[4];
  if (row < M){
    const float* ap = A + (size_t)row*128 + quad*8;
#pragma unroll
    for (int c = 0; c < 4; c++){
      f32x4 lo = *(const f32x4*)(ap + c*32);
      f32x4 hi = *(const f32x4*)(ap + c*32 + 4);
      short8 t;
      t[0]=(short)f2bf(lo[0]); t[1]=(short)f2bf(lo[1]);
      t[2]=(short)f2bf(lo[2]); t[3]=(short)f2bf(lo[3]);
      t[4]=(short)f2bf(hi[0]); t[5]=(short)f2bf(hi[1]);
      t[6]=(short)f2bf(hi[2]); t[7]=(short)f2bf(hi[3]);
      af[c] = t;
    }
  } else {
    short8 z = {0,0,0,0,0,0,0,0};
#pragma unroll
    for (int c = 0; c < 4; c++) af[c] = z;
  }
  f32x4 acc[4];
#pragma unroll
  for (int nt = 0; nt < 4; nt++) acc[nt] = (f32x4){0.f,0.f,0.f,0.f};
#pragma unroll
  for (int nt = 0; nt < 4; nt++){
    const u16* bp = &BT[(nt*16 + lm) * BTSTR + quad*8];
#pragma unroll
    for (int c = 0; c < 4; c++){
      short8 bf = *(const short8*)(bp + c*32);
      acc[nt] = __builtin_amdgcn_mfma_f32_16x16x32_bf16(af[c], bf, acc[nt], 0, 0, 0);
    }
  }
#pragma unroll
  for (int nt = 0; nt < 4; nt++){
    int col = bn + nt*16 + lm;
    float bb = bias[col];
#pragma unroll
    for (int i = 0; i < 4; i++){
      int r = bm + wave*16 + quad*4 + i;
      if (r < M) C[(size_t)r*ldc + col] = f2bf(acc[nt][i] + bb);
    }
  }
}

// Fused q-GEMM: all 3 node types in one dispatch. grid = (2, 1252).
// by: [0,782) gene, [782,1095) disease, [1095,1252) drug.
__global__ __launch_bounds__(256) void mfma_gemm_q(
    const float* __restrict__ X, const float* __restrict__ Wl,
    const float* __restrict__ bl, u16* __restrict__ qg)
{
  __shared__ u16 BT[64 * BTSTR];
  int by = blockIdx.y;
  int t, bm, M, roff;
  if (by < 782)       { t = 0; bm = by*64;          M = 50000; roff = 0; }
  else if (by < 1095) { t = 1; bm = (by-782)*64;    M = 20000; roff = 50000; }
  else                { t = 2; bm = (by-1095)*64;   M = 10000; roff = 70000; }
  gemm_tile_f32A(X + (size_t)roff*128,
                 Wl + (size_t)t*49152 + 128, 384,
                 bl + (size_t)t*384 + 128,
                 qg + (size_t)roff*128, 128,
                 M, bm, blockIdx.x*64, BT);
}

// Fused kv-GEMM: all 4 relations in one dispatch. grid = (4, 1878).
// by: [0,782) r0, [782,1564) r1, [1564,1721) r2, [1721,1878) r3.
__global__ __launch_bounds__(256) void mfma_gemm_kv(
    const float* __restrict__ X, const float* __restrict__ Weffl,
    const float* __restrict__ beffl, u16* __restrict__ kv)
{
  __shared__ u16 BT[64 * BTSTR];
  int by = blockIdx.y;
  int r, bm, M, soff, ooff;
  if (by < 782)       { r = 0; bm = by*64;          M = 50000; soff = 0;     ooff = 0; }
  else if (by < 1564) { r = 1; bm = (by-782)*64;    M = 50000; soff = 0;     ooff = 50000; }
  else if (by < 1721) { r = 2; bm = (by-1564)*64;   M = 10000; soff = 70000; ooff = 100000; }
  else                { r = 3; bm = (by-1721)*64;   M = 10000; soff = 70000; ooff = 110000; }
  gemm_tile_f32A(X + (size_t)soff*128,
                 Weffl + (size_t)r*32768, 256,
                 beffl + (size_t)r*256,
                 kv + (size_t)ooff*256, 256,
                 M, bm, blockIdx.x*64, BT);
}

// Fused out-GEMM: A = G(bf16), epilogue skip+relu+residual on X(fp32). grid = (2, 1252).
__global__ __launch_bounds__(256) void mfma_gemm_out(
    const u16* __restrict__ Gall, const float* __restrict__ Wl,
    const float* __restrict__ bl, const float* __restrict__ skipl,
    float* __restrict__ Xall)
{
  __shared__ u16 BT[64 * BTSTR];
  int by = blockIdx.y;
  int t, bm, M, roff;
  if (by < 782)       { t = 0; bm = by*64;          M = 50000; roff = 0; }
  else if (by < 1095) { t = 1; bm = (by-782)*64;    M = 20000; roff = 50000; }
  else                { t = 2; bm = (by-1095)*64;   M = 10000; roff = 70000; }
  const u16* G = Gall + (size_t)roff*128;
  const float* B = Wl + (size_t)t*16384;
  const float* bias = bl + (size_t)t*128;
  float* X = Xall + (size_t)roff*128;

  int tid = threadIdx.x;
  int bn = blockIdx.x * 64;
  {
    int n = tid & 63, k0 = tid >> 6;
#pragma unroll
    for (int i = 0; i < 32; i++){
      int k = k0 + i*4;
      BT[n*BTSTR + k] = f2bf(B[(size_t)k*128 + bn + n]);
    }
  }
  __syncthreads();
  int lane = tid & 63, wave = tid >> 6;
  int quad = lane >> 4, lm = lane & 15;
  int row = bm + wave*16 + lm;
  short8 af[4];
  if (row < M){
    const u16* gp = G + (size_t)row*128 + quad*8;
#pragma unroll
    for (int c = 0; c < 4; c++) af[c] = *(const short8*)(gp + c*32);  // native bf16
  } else {
    short8 z = {0,0,0,0,0,0,0,0};
#pragma unroll
    for (int c = 0; c < 4; c++) af[c] = z;
  }
  f32x4 acc[4];
#pragma unroll
  for (int nt = 0; nt < 4; nt++) acc[nt] = (f32x4){0.f,0.f,0.f,0.f};
#pragma unroll
  for (int nt = 0; nt < 4; nt++){
    const u16* bp = &BT[(nt*16 + lm) * BTSTR + quad*8];
#pragma unroll
    for (int c = 0; c < 4; c++){
      short8 bf = *(const short8*)(bp + c*32);
      acc[nt] = __builtin_amdgcn_mfma_f32_16x16x32_bf16(af[c], bf, acc[nt], 0, 0, 0);
    }
  }
  float a_s = 1.f / (1.f + expf(-skipl[t]));
  float b_s = 1.f - a_s;
#pragma unroll
  for (int nt = 0; nt < 4; nt++){
    int col = bn + nt*16 + lm;
    float bb = bias[col];
#pragma unroll
    for (int i = 0; i < 4; i++){
      int r = bm + wave*16 + quad*4 + i;
      if (r < M){
        float* xp = X + (size_t)r*128 + col;
        float x = *xp;
        float o = acc[nt][i] + bb;
        *xp = fmaxf(a_s*o + b_s*x, 0.f) + x;
      }
    }
  }
}

// ---------------- attention: one thread per (dst,head); 4-edge batched loads ----------------

__global__ __launch_bounds__(256) void attn_kernel(
    u16* __restrict__ qg,                   // NTOT x 128 bf16: q in, gelu(out) out
    const u16* __restrict__ kv,             // NSRC x 256 bf16: [k | v]
    const float* __restrict__ prel,         // + l*32
    const int* __restrict__ rowp, const int* __restrict__ cnt,
    const int* __restrict__ elist)
{
  int gid = blockIdx.x * 256 + threadIdx.x;
  int n = gid >> 3, h = gid & 7;
  if (n >= NTOT) return;
  float sc0 = prel[0*8+h]*0.25f, sc1 = prel[1*8+h]*0.25f,
        sc2 = prel[2*8+h]*0.25f, sc3 = prel[3*8+h]*0.25f;
  float q[16];
  load16bf(qg + (size_t)n * 128 + h*16, q);
  float acc[16] = {};
  float dsum = 0.f;
  int start = rowp[n], c = cnt[n];

  auto edge = [&](int ev, uint4 ka, uint4 kb, uint4 va, uint4 vb){
    float ke[16], ve[16];
    unp4(ka, ke); unp4(kb, ke + 8);
    unp4(va, ve); unp4(vb, ve + 8);
    float a = 0.f;
#pragma unroll
    for (int d = 0; d < 16; d++) a += q[d] * ke[d];
    int r = ev & 3;
    float s = (r == 0) ? sc0 : (r == 1) ? sc1 : (r == 2) ? sc2 : sc3;
    float ex = expf(a * s);
    dsum += ex;
#pragma unroll
    for (int d = 0; d < 16; d++) acc[d] += ex * ve[d];
  };

  int ii = 0;
#pragma unroll 1
  for (; ii + 4 <= c; ii += 4){
    // 4 independent elist loads (8 head-lanes share addresses -> coalesced broadcast)
    int e0 = elist[start + ii + 0], e1 = elist[start + ii + 1],
        e2 = elist[start + ii + 2], e3 = elist[start + ii + 3];
    const u16* p0 = kv + (size_t)(e0 >> 2) * 256 + h*16;
    const u16* p1 = kv + (size_t)(e1 >> 2) * 256 + h*16;
    const u16* p2 = kv + (size_t)(e2 >> 2) * 256 + h*16;
    const u16* p3 = kv + (size_t)(e3 >> 2) * 256 + h*16;
    // issue all 16 loads before any compute -> deep MLP
    uint4 k0a = *(const uint4*)p0,         k0b = *(const uint4*)(p0 + 8);
    uint4 k1a = *(const uint4*)p1,         k1b = *(const uint4*)(p1 + 8);
    uint4 k2a = *(const uint4*)p2,         k2b = *(const uint4*)(p2 + 8);
    uint4 k3a = *(const uint4*)p3,         k3b = *(const uint4*)(p3 + 8);
    uint4 v0a = *(const uint4*)(p0 + 128), v0b = *(const uint4*)(p0 + 136);
    uint4 v1a = *(const uint4*)(p1 + 128), v1b = *(const uint4*)(p1 + 136);
    uint4 v2a = *(const uint4*)(p2 + 128), v2b = *(const uint4*)(p2 + 136);
    uint4 v3a = *(const uint4*)(p3 + 128), v3b = *(const uint4*)(p3 + 136);
    edge(e0, k0a, k0b, v0a, v0b);
    edge(e1, k1a, k1b, v1a, v1b);
    edge(e2, k2a, k2b, v2a, v2b);
    edge(e3, k3a, k3b, v3a, v3b);
  }
  for (; ii < c; ii++){
    int ev = elist[start + ii];
    const u16* p = kv + (size_t)(ev >> 2) * 256 + h*16;
    uint4 ka = *(const uint4*)p,         kb = *(const uint4*)(p + 8);
    uint4 va = *(const uint4*)(p + 128), vb = *(const uint4*)(p + 136);
    edge(ev, ka, kb, va, vb);
  }

  float inv = (c > 0) ? 1.f / dsum : 0.f;
  u16 o[16];
#pragma unroll
  for (int d = 0; d < 16; d++){
    float x = acc[d] * inv;
    o[d] = f2bf(0.5f * x * (1.f + erff(x * 0.70710678118654752f)));
  }
  uint4 p0, p1;
  p0.x = o[0]|(o[1]<<16);   p0.y = o[2]|(o[3]<<16);
  p0.z = o[4]|(o[5]<<16);   p0.w = o[6]|(o[7]<<16);
  p1.x = o[8]|(o[9]<<16);   p1.y = o[10]|(o[11]<<16);
  p1.z = o[12]|(o[13]<<16); p1.w = o[14]|(o[15]<<16);
  u16* op = qg + (size_t)n * 128 + h*16;
  *(uint4*)op = p0; *(uint4*)(op + 8) = p1;
}

// ---------------- host ----------------

extern "C" void kernel_launch(void* const* d_in, const int* in_sizes, int n_in,
                              void* d_out, int out_size, void* d_ws, size_t ws_size,
                              hipStream_t stream)
{
  const float* xg   = (const float*)d_in[0];
  const float* xd   = (const float*)d_in[1];
  const float* xr_  = (const float*)d_in[2];
  const float* Wkqv = (const float*)d_in[3];
  const float* bkqv = (const float*)d_in[4];
  const float* Ak   = (const float*)d_in[5];
  const float* Av   = (const float*)d_in[6];
  const float* prel = (const float*)d_in[7];
  const float* Wout = (const float*)d_in[8];
  const float* bout = (const float*)d_in[9];
  const float* skip = (const float*)d_in[10];
  const int* ei[4] = {(const int*)d_in[11], (const int*)d_in[12],
                      (const int*)d_in[13], (const int*)d_in[14]};

  static const int ES_[4]  = {300000, 150000, 100000, 50000};
  static const int DT_[4]  = {0, 0, 0, 1};   // placeholder, replaced below
  (void)DT_;
  static const int OFF_[4] = {0, 50000, 70000, 80000};
  static const int DTT_[4] = {0, 1, 0, 1};
  static const int RN_[4]  = {0, 50000, 100000, 110000};

  float* X = (float*)d_out;

  char* p = (char*)d_ws;
  auto alloc = [&](size_t b)->void*{ void* r = (void*)p; p += (b + 255) & ~(size_t)255; return r; };
  int*   cnt  = (int*)  alloc((size_t)NTOT * 4);
  int*   rowp = (int*)  alloc((size_t)NTOT * 4);
  int*   cur  = (int*)  alloc((size_t)NTOT * 4);
  int*   bsum = (int*)  alloc(512 * 4);
  int*   elist= (int*)  alloc((size_t)ETOT * 4);
  float* Weff = (float*)alloc((size_t)8 * 32768 * 4);
  float* beff = (float*)alloc((size_t)8 * 256 * 4);
  u16*   qg   = (u16*)  alloc((size_t)NTOT * 128 * 2);    // 20.5 MB bf16
  u16*   kv   = (u16*)  alloc((size_t)NSRC * 256 * 2);    // 61.4 MB bf16
  (void)ws_size; (void)in_sizes; (void)n_in; (void)out_size;

  copy_init<<<10000, 256, 0, stream>>>(xg, xd, xr_, X);
  zero_cc<<<313, 256, 0, stream>>>(cnt, cur);

  for (int r = 0; r < 4; r++)
    count_edges<<<(ES_[r]+255)/256, 256, 0, stream>>>(ei[r], ES_[r], OFF_[DTT_[r]], cnt);
  scan_partial<<<313, 256, 0, stream>>>(cnt, rowp, bsum);
  scan_block<<<1, 256, 0, stream>>>(bsum, 313);
  scan_add<<<313, 256, 0, stream>>>(rowp, bsum);
  for (int r = 0; r < 4; r++)
    scatter_edges<<<(ES_[r]+255)/256, 256, 0, stream>>>(ei[r], ES_[r], OFF_[DTT_[r]],
                                                        RN_[r], r, rowp, cur, elist);

  build_weff<<<dim3(128, 8), 256, 0, stream>>>(Wkqv, Ak, Av, Weff);
  build_beff<<<8, 256, 0, stream>>>(bkqv, Ak, Av, beff);

  for (int l = 0; l < 2; l++){
    mfma_gemm_q<<<dim3(2, 1252), 256, 0, stream>>>(
        X, Wkqv + (size_t)l*3*49152, bkqv + (size_t)l*3*384, qg);
    mfma_gemm_kv<<<dim3(4, 1878), 256, 0, stream>>>(
        X, Weff + (size_t)l*4*32768, beff + (size_t)l*4*256, kv);
    attn_kernel<<<2500, 256, 0, stream>>>(qg, kv, prel + l*32, rowp, cnt, elist);
    mfma_gemm_out<<<dim3(2, 1252), 256, 0, stream>>>(
        qg, Wout + (size_t)l*3*16384, bout + (size_t)l*3*128, skip + l*3, X);
  }
}